// Round 1
// baseline (446.745 us; speedup 1.0000x reference)
//
#include <hip/hip_runtime.h>
#include <math.h>

#define B_    4
#define K_    2048
#define D_    1024
#define H_    16
#define NCTX_ 1024

typedef unsigned short ushort_t;
typedef _Float16 f16;
typedef __attribute__((ext_vector_type(8))) _Float16 f16x8;
typedef __attribute__((ext_vector_type(4))) float f32x4;

union U4 {
  f16 h[4];
  ushort4 u;
};

__device__ __forceinline__ void gload16(const void* g, void* l) {
  __builtin_amdgcn_global_load_lds(
      (const __attribute__((address_space(1))) unsigned int*)g,
      (__attribute__((address_space(3))) unsigned int*)l, 16, 0, 0);
}

// ---------------------------------------------------------------------------
// Kernel 1: partition scan (verified R1-R4).
// ---------------------------------------------------------------------------
__global__ __launch_bounds__(256) void partition_kernel(
    const unsigned char* __restrict__ isctx, int* __restrict__ pos,
    int* __restrict__ ipos) {
  const int b = blockIdx.x;
  const int tid = threadIdx.x;
  const int wid = tid >> 6, lane = tid & 63;
  __shared__ int csum[4];
  __shared__ int waveTot[4];
  __shared__ int strideSh;

  int cnt = 0;
  for (int i = 0; i < 32; ++i) cnt += (isctx[tid * 32 + i] != 0);
  for (int off = 32; off; off >>= 1) cnt += __shfl_down(cnt, off, 64);
  if (lane == 0) csum[wid] = cnt;
  __syncthreads();
  if (tid == 0) {
    int t = csum[0] + csum[1] + csum[2] + csum[3];
    strideSh = (t > 2048) ? 1 : ((t > 768) ? 4 : 8);
  }
  __syncthreads();
  const int stride = strideSh;

  const unsigned char* base = isctx + (size_t)b * K_ * stride;
  int f[8];
  int s = 0;
  for (int i = 0; i < 8; ++i) {
    f[i] = base[(size_t)(tid * 8 + i) * stride] != 0;
    s += f[i];
  }
  int inc = s;
  for (int off = 1; off < 64; off <<= 1) {
    int v = __shfl_up(inc, off, 64);
    if (lane >= off) inc += v;
  }
  if (lane == 63) waveTot[wid] = inc;
  __syncthreads();
  int wOff = 0;
  for (int w = 0; w < wid; ++w) wOff += waveTot[w];
  int run = wOff + inc - s;
  for (int i = 0; i < 8; ++i) {
    int k = tid * 8 + i;
    int p;
    if (f[i]) {
      p = run;
      run++;
    } else {
      p = NCTX_ + k - run;
    }
    pos[b * K_ + k] = p;
    ipos[b * K_ + p] = k;
  }
}

// ---------------------------------------------------------------------------
// Kernel 2: RoPE + permute-gather -> f16 token buffer.
// ---------------------------------------------------------------------------
__global__ __launch_bounds__(256) void rope_kernel(
    const float* __restrict__ x, const float* __restrict__ coords,
    const float* __restrict__ cache, const int* __restrict__ ipos,
    f16* __restrict__ tok) {
  const int row = blockIdx.x;
  const int b = row >> 11;
  const int r = row & (K_ - 1);
  const int k = ipos[row];
  const int t = threadIdx.x;

  const float cy = coords[(size_t)(b * K_ + k) * 2 + 0];
  const float cx = coords[(size_t)(b * K_ + k) * 2 + 1];
  const int ypos = (int)fminf(fmaxf(cy / 224.0f * 1023.0f, 0.0f), 1023.0f);
  const int xpos = (int)fminf(fmaxf(cx / 224.0f * 1023.0f, 0.0f), 1023.0f);

  const float4 v = ((const float4*)(x + ((size_t)b * K_ + k) * D_))[t];
  const int e = 4 * t;
  const float* crow;
  int coff;
  if (e < 512) {
    crow = cache + (size_t)xpos * 512;
    coff = e;
  } else {
    crow = cache + (size_t)ypos * 512;
    coff = e - 512;
  }
  const float4 cs = *(const float4*)(crow + coff);
  float o[4];
  o[0] = v.x * cs.x - v.y * cs.y;
  o[1] = v.x * cs.y + v.y * cs.x;
  o[2] = v.z * cs.z - v.w * cs.w;
  o[3] = v.z * cs.w + v.w * cs.z;
  U4 h;
#pragma unroll
  for (int i = 0; i < 4; ++i) h.h[i] = (f16)o[i];
  ((ushort4*)(tok + ((size_t)b * K_ + r) * D_))[t] = h.u;
}

// ---------------------------------------------------------------------------
// Kernel 3: all weights fp32 -> f16, concatenated:
// [0,3M) ctx_in | [3M,5M) tgt_in kv | [5M,6M) tgt_in q | [6M,7M) ctx_out |
// [7M,8M) tgt_out   (M = 1048576 floats)
// ---------------------------------------------------------------------------
__global__ __launch_bounds__(256) void cvt_all(
    const float* __restrict__ ctx_in_w, const float* __restrict__ tgt_in_w,
    const float* __restrict__ ctx_out_w, const float* __restrict__ tgt_out_w,
    f16* __restrict__ dst) {
  const int i4 = blockIdx.x * 256 + threadIdx.x;  // 0..2097151
  const int f = i4 * 4;
  const float* src;
  if (f < 3145728) src = ctx_in_w + f;
  else if (f < 5242880) src = tgt_in_w + (f - 3145728 + 1048576);
  else if (f < 6291456) src = tgt_in_w + (f - 5242880);
  else if (f < 7340032) src = ctx_out_w + (f - 6291456);
  else src = tgt_out_w + (f - 7340032);
  const float4 v = *(const float4*)src;
  U4 u;
  u.h[0] = (f16)v.x;
  u.h[1] = (f16)v.y;
  u.h[2] = (f16)v.z;
  u.h[3] = (f16)v.w;
  ((ushort4*)dst)[i4] = u.u;
}

// ---------------------------------------------------------------------------
// GEMM core, BK=64, DOUBLE-BUFFERED (T3 minimum 2-phase):
// prologue-stage tile 0; in-loop stage tile k+1 into the other 32KB buffer,
// compute tile k, ONE vmcnt(0)+barrier per K-step. The prefetch has the
// whole compute phase (~350 cy of ds_read+MFMA) to land, so the barrier
// drain no longer serializes HBM/L2 latency. LDS 64 KB -> 2 blocks/CU
// (grid 1536 = exactly 3 full rounds, no tail).
// ---------------------------------------------------------------------------
#define GEMM_STAGE(AP, WP, Kd, k0s, bb)                                       \
  _Pragma("unroll") for (int j = 0; j < 8; ++j) {                             \
    const int c = ((j & 3) * 4 + wave) * 64 + lane;                           \
    const int q = c >> 7, r = c & 127;                                        \
    const f16* g = (j < 4) ? (AP + (size_t)r * Kd + (k0s) + q * 8)            \
                           : (WP + (size_t)r * Kd + (k0s) + q * 8);           \
    gload16(g, &lds[(bb) + (j >> 2) * 8192 + c * 8]);                         \
  }

#define GEMM_CORE64(AP, WP, Kd)                                               \
  f32x4 acc[4][4];                                                            \
  {                                                                           \
    const f32x4 z = {0.f, 0.f, 0.f, 0.f};                                     \
    for (int i = 0; i < 4; ++i)                                               \
      for (int j = 0; j < 4; ++j) acc[i][j] = z;                              \
  }                                                                           \
  GEMM_STAGE(AP, WP, Kd, 0, 0)                                                \
  __syncthreads();                                                            \
  for (int k0 = 0, cur = 0; k0 < Kd; k0 += 64, cur ^= 1) {                    \
    if (k0 + 64 < Kd) {                                                       \
      GEMM_STAGE(AP, WP, Kd, k0 + 64, (cur ^ 1) * 16384)                      \
    }                                                                         \
    const int cb = cur * 16384;                                               \
    _Pragma("unroll") for (int kh = 0; kh < 2; ++kh) {                        \
      f16x8 af[4], wf[4];                                                     \
      _Pragma("unroll") for (int i = 0; i < 4; ++i) {                         \
        af[i] = *(const f16x8*)&lds[cb + ((kh * 4 + quad) * 128 + wm +        \
                                          i * 16 + m16) * 8];                 \
        wf[i] = *(const f16x8*)&lds[cb + 8192 + ((kh * 4 + quad) * 128 + wn + \
                                                 i * 16 + m16) * 8];          \
      }                                                                       \
      _Pragma("unroll") for (int i = 0; i < 4; ++i)                           \
          _Pragma("unroll") for (int j = 0; j < 4; ++j)                       \
        acc[i][j] = __builtin_amdgcn_mfma_f32_16x16x32_f16(                   \
            af[i], wf[j], acc[i][j], 0, 0, 0);                                \
    }                                                                         \
    __syncthreads();                                                          \
  }

// ---------------------------------------------------------------------------
// Kernel 4: merged projection GEMM. grid (48, 8, 4):
//   nb < 40: ctx rows x [ctx_in QKV (3072) | tgt_in KV (2048)] -> qkvc / kvt
//   nb >= 40: tgt rows x tgt_in Q (1024) -> qt
// ---------------------------------------------------------------------------
__global__ __launch_bounds__(256) void gemm_proj(
    const f16* __restrict__ tok, const f16* __restrict__ wcat,
    const float* __restrict__ ctx_in_b, const float* __restrict__ tgt_in_b,
    f16* __restrict__ qkvc, f16* __restrict__ kvt, f16* __restrict__ qt) {
  __shared__ f16 lds[32768];
  const int tid = threadIdx.x;
  const int wave = tid >> 6, lane = tid & 63;
  const int quad = lane >> 4, m16 = lane & 15;
  const int nb = blockIdx.x, mb = blockIdx.y, b = blockIdx.z;
  const int wm = (wave & 1) << 6, wn = (wave >> 1) << 6;
  const int m0 = mb * 128;
  const bool isQ = nb >= 40;
  const int n0 = isQ ? (nb - 40) * 128 : nb * 128;
  const f16* AP = tok + (size_t)b * K_ * D_ +
                  (isQ ? (size_t)NCTX_ * D_ : (size_t)0) + (size_t)m0 * D_;
  const f16* WP = wcat + (isQ ? (size_t)5242880 : (size_t)0) +
                  (size_t)n0 * D_;

  GEMM_CORE64(AP, WP, D_)

#pragma unroll
  for (int j = 0; j < 4; ++j) {
    const int col = n0 + wn + j * 16 + m16;
    float bv;
    f16* dst;
    int ldc, dcol;
    if (isQ) {
      bv = tgt_in_b[col];
      dst = qt + (size_t)b * NCTX_ * D_;
      ldc = D_;
      dcol = col;
    } else if (col < 3072) {
      bv = ctx_in_b[col];
      dst = qkvc + (size_t)b * NCTX_ * 3072;
      ldc = 3072;
      dcol = col;
    } else {
      bv = tgt_in_b[D_ + col - 3072];
      dst = kvt + (size_t)b * NCTX_ * 2048;
      ldc = 2048;
      dcol = col - 3072;
    }
#pragma unroll
    for (int i = 0; i < 4; ++i) {
      const int mr = m0 + wm + i * 16 + quad * 4;
#pragma unroll
      for (int r = 0; r < 4; ++r)
        dst[(size_t)(mr + r) * ldc + dcol] = (f16)(acc[i][j][r] + bv);
    }
  }
}

// ---------------------------------------------------------------------------
// Kernel 5: merged output projections. grid (8, 8, 8): b = z&3, sel = z>>2.
// fp32 output scattered to original token order (16-lane 64B segments ->
// already fully coalesced).
// ---------------------------------------------------------------------------
__global__ __launch_bounds__(256) void gemm_out(
    const f16* __restrict__ Atok, const f16* __restrict__ Wbase,
    const float* __restrict__ bias_ctx, const float* __restrict__ bias_tgt,
    const int* __restrict__ ipos, float* __restrict__ out) {
  __shared__ f16 lds[32768];
  const int tid = threadIdx.x;
  const int wave = tid >> 6, lane = tid & 63;
  const int quad = lane >> 4, m16 = lane & 15;
  const int n0 = blockIdx.x * 128, m0 = blockIdx.y * 128;
  const int b = blockIdx.z & 3, sel = blockIdx.z >> 2;
  const int wm = (wave & 1) << 6, wn = (wave >> 1) << 6;
  const f16* AP = Atok + (size_t)b * K_ * D_ + (size_t)sel * NCTX_ * D_ +
                  (size_t)m0 * D_;
  const f16* WP = Wbase + (size_t)sel * 1048576 + (size_t)n0 * D_;
  const float* bias = sel ? bias_tgt : bias_ctx;

  GEMM_CORE64(AP, WP, D_)

#pragma unroll
  for (int j = 0; j < 4; ++j) {
    const int col = n0 + wn + j * 16 + m16;
    const float bv = bias[col];
#pragma unroll
    for (int i = 0; i < 4; ++i) {
      const int mr = m0 + wm + i * 16 + quad * 4;
#pragma unroll
      for (int r = 0; r < 4; ++r) {
        const int orow = ipos[b * K_ + sel * NCTX_ + mr + r];
        out[(size_t)b * K_ * D_ + (size_t)orow * D_ + col] =
            acc[i][j][r] + bv;
      }
    }
  }
}

// ---------------------------------------------------------------------------
// Kernel 6: V transpose (16-bit moves).
// ---------------------------------------------------------------------------
__global__ __launch_bounds__(256) void vtrans_kernel(
    const ushort_t* __restrict__ V, long long sVb, int ldv, int coloff,
    ushort_t* __restrict__ Vt) {
  __shared__ __align__(16) ushort_t tile[64][72];
  const int tblk = blockIdx.x, h = blockIdx.y, b = blockIdx.z;
  const int tid = threadIdx.x;
  const ushort_t* src =
      V + (long long)b * sVb + (size_t)(tblk * 64) * ldv + coloff + h * 64;
#pragma unroll
  for (int j = 0; j < 2; ++j) {
    const int c = j * 256 + tid;
    const int r = c >> 3, dc = c & 7;
    *(uint4*)&tile[r][dc * 8] = *(const uint4*)(src + (size_t)r * ldv + dc * 8);
  }
  __syncthreads();
  ushort_t* dst = Vt + (size_t)(b * H_ + h) * 64 * 1024 + tblk * 64;
#pragma unroll
  for (int j = 0; j < 2; ++j) {
    const int c = j * 256 + tid;
    const int d = c >> 3, tc = c & 7;
    union {
      ushort_t u[8];
      uint4 v;
    } t;
#pragma unroll
    for (int i = 0; i < 8; ++i) t.u[i] = tile[tc * 8 + i][d];
    *(uint4*)(dst + (size_t)d * 1024 + tc * 8) = t.v;
  }
}

// ---------------------------------------------------------------------------
// Kernel 7: MFMA flash attention, f16, single-f16 output.
// K/V double-buffered: stage kt+1 while computing kt, ONE barrier per kt
// (was 2 full drains). Q fragments hoisted out of the loop (loop-invariant).
// s_setprio(1) around the MFMA clusters (measured +4-7% on attn, m191).
// LDS: Q 8KB + K 2x8KB + V 2x8KB + P 8KB = 48KB -> 3 blocks/CU.
// ---------------------------------------------------------------------------
__global__ __launch_bounds__(256) void attn_mfma(
    const f16* __restrict__ Qp, long long sQb, int ldq,
    const f16* __restrict__ Kp, long long sKb, int ldk,
    const f16* __restrict__ Vt, f16* __restrict__ O, long long sOb) {
  __shared__ f16 Qs[4096];
  __shared__ f16 Ks[2][4096];
  __shared__ f16 Vs[2][4096];
  __shared__ f16 Ps[4096];
  const int tid = threadIdx.x, wave = tid >> 6, lane = tid & 63;
  const int quad = lane >> 4, m16 = lane & 15;
  const int q0 = blockIdx.x * 64, h = blockIdx.y, b = blockIdx.z;
  const f16* Qb = Qp + (long long)b * sQb + h * 64;
  const f16* Kb = Kp + (long long)b * sKb + h * 64;
  const f16* Vb = Vt + (size_t)(b * H_ + h) * 64 * 1024;

  // Prologue: stage Q + K/V tile 0 in one drain.
#pragma unroll
  for (int j = 0; j < 2; ++j) {
    const int c = j * 256 + wave * 64 + lane;
    gload16(Qb + (size_t)(q0 + (c & 63)) * ldq + (c >> 6) * 8, &Qs[c * 8]);
    gload16(Kb + (size_t)(c & 63) * ldk + (c >> 6) * 8, &Ks[0][c * 8]);
    gload16(Vb + (size_t)(c & 63) * 1024 + (c >> 6) * 8, &Vs[0][c * 8]);
  }
  float m_run[4], l_run[4];
#pragma unroll
  for (int r = 0; r < 4; ++r) {
    m_run[r] = -1e30f;
    l_run[r] = 0.f;
  }
  f32x4 Oa[4];
  const f32x4 z = {0.f, 0.f, 0.f, 0.f};
#pragma unroll
  for (int j = 0; j < 4; ++j) Oa[j] = z;
  __syncthreads();

  const f16x8 qf0 = *(const f16x8*)&Qs[(quad * 64 + wave * 16 + m16) * 8];
  const f16x8 qf1 =
      *(const f16x8*)&Qs[((4 + quad) * 64 + wave * 16 + m16) * 8];

  for (int kt = 0; kt < 16; ++kt) {
    const int cur = kt & 1;
    // Prefetch next K/V tile into the other buffer; lands during compute.
    if (kt < 15) {
#pragma unroll
      for (int j = 0; j < 2; ++j) {
        const int c = j * 256 + wave * 64 + lane;
        gload16(Kb + (size_t)((kt + 1) * 64 + (c & 63)) * ldk + (c >> 6) * 8,
                &Ks[cur ^ 1][c * 8]);
        gload16(Vb + (size_t)(c & 63) * 1024 + (kt + 1) * 64 + (c >> 6) * 8,
                &Vs[cur ^ 1][c * 8]);
      }
    }
    f32x4 S[4];
    __builtin_amdgcn_s_setprio(1);
#pragma unroll
    for (int jn = 0; jn < 4; ++jn) {
      S[jn] = z;
      const f16x8 kf0 =
          *(const f16x8*)&Ks[cur][(quad * 64 + jn * 16 + m16) * 8];
      const f16x8 kf1 =
          *(const f16x8*)&Ks[cur][((4 + quad) * 64 + jn * 16 + m16) * 8];
      S[jn] = __builtin_amdgcn_mfma_f32_16x16x32_f16(qf0, kf0, S[jn], 0, 0, 0);
      S[jn] = __builtin_amdgcn_mfma_f32_16x16x32_f16(qf1, kf1, S[jn], 0, 0, 0);
    }
    __builtin_amdgcn_s_setprio(0);
#pragma unroll
    for (int jn = 0; jn < 4; ++jn) S[jn] *= 0.125f;
    float mnew[4], al[4], rs[4];
#pragma unroll
    for (int r = 0; r < 4; ++r) {
      float mx = fmaxf(fmaxf(S[0][r], S[1][r]), fmaxf(S[2][r], S[3][r]));
      mx = fmaxf(mx, __shfl_xor(mx, 1, 64));
      mx = fmaxf(mx, __shfl_xor(mx, 2, 64));
      mx = fmaxf(mx, __shfl_xor(mx, 4, 64));
      mx = fmaxf(mx, __shfl_xor(mx, 8, 64));
      mnew[r] = fmaxf(m_run[r], mx);
      al[r] = __expf(m_run[r] - mnew[r]);
      m_run[r] = mnew[r];
      rs[r] = 0.f;
    }
#pragma unroll
    for (int jn = 0; jn < 4; ++jn)
#pragma unroll
      for (int r = 0; r < 4; ++r) {
        const float p = __expf(S[jn][r] - mnew[r]);
        S[jn][r] = p;
        rs[r] += p;
      }
#pragma unroll
    for (int r = 0; r < 4; ++r) {
      float s = rs[r];
      s += __shfl_xor(s, 1, 64);
      s += __shfl_xor(s, 2, 64);
      s += __shfl_xor(s, 4, 64);
      s += __shfl_xor(s, 8, 64);
      l_run[r] = l_run[r] * al[r] + s;
    }
#pragma unroll
    for (int j = 0; j < 4; ++j) {
      Oa[j][0] *= al[0];
      Oa[j][1] *= al[1];
      Oa[j][2] *= al[2];
      Oa[j][3] *= al[3];
    }
    f16* Pw = Ps + wave * 1024;
#pragma unroll
    for (int jn = 0; jn < 4; ++jn)
#pragma unroll
      for (int r = 0; r < 4; ++r)
        Pw[((jn * 2 + (m16 >> 3)) * 16 + quad * 4 + r) * 8 + (m16 & 7)] =
            (f16)S[jn][r];
    const f16x8 pf0 = *(const f16x8*)&Pw[(quad * 16 + m16) * 8];
    const f16x8 pf1 = *(const f16x8*)&Pw[((4 + quad) * 16 + m16) * 8];
    __builtin_amdgcn_s_setprio(1);
#pragma unroll
    for (int jd = 0; jd < 4; ++jd) {
      const f16x8 vf0 =
          *(const f16x8*)&Vs[cur][(quad * 64 + jd * 16 + m16) * 8];
      const f16x8 vf1 =
          *(const f16x8*)&Vs[cur][((4 + quad) * 64 + jd * 16 + m16) * 8];
      Oa[jd] = __builtin_amdgcn_mfma_f32_16x16x32_f16(pf0, vf0, Oa[jd], 0, 0, 0);
      Oa[jd] = __builtin_amdgcn_mfma_f32_16x16x32_f16(pf1, vf1, Oa[jd], 0, 0, 0);
    }
    __builtin_amdgcn_s_setprio(0);
    __syncthreads();
  }
#pragma unroll
  for (int jd = 0; jd < 4; ++jd)
#pragma unroll
    for (int r = 0; r < 4; ++r) {
      const float v = Oa[jd][r] / l_run[r];
      const size_t off = (long long)b * sOb +
                         (size_t)(q0 + wave * 16 + quad * 4 + r) * D_ + h * 64 +
                         jd * 16 + m16;
      O[off] = (f16)v;
    }
}

// ---------------------------------------------------------------------------
extern "C" void kernel_launch(void* const* d_in, const int* in_sizes, int n_in,
                              void* d_out, int out_size, void* d_ws,
                              size_t ws_size, hipStream_t stream) {
  const float* x = (const float*)d_in[0];
  const float* coords = (const float*)d_in[1];
  const unsigned char* isctx = (const unsigned char*)d_in[2];
  const float* rope = (const float*)d_in[3];
  const float* ctx_in_w = (const float*)d_in[4];
  const float* ctx_in_b = (const float*)d_in[5];
  const float* ctx_out_w = (const float*)d_in[6];
  const float* ctx_out_b = (const float*)d_in[7];
  const float* tgt_in_w = (const float*)d_in[8];
  const float* tgt_in_b = (const float*)d_in[9];
  const float* tgt_out_w = (const float*)d_in[10];
  const float* tgt_out_b = (const float*)d_in[11];
  float* out = (float*)d_out;

  // ws layout (f16 units): tok 8M | wcat 8M | qkvc 12M | kvt 8M | qt 4M |
  // vt 4M | pos/ipos ints
  f16* ws = (f16*)d_ws;
  f16* tok = ws;
  f16* wcat = tok + 8388608;
  f16* qkvc = wcat + 8388608;
  f16* kvt = qkvc + 12582912;
  f16* qt = kvt + 8388608;
  f16* vt = qt + 4194304;
  int* pos = (int*)(vt + 4194304);
  int* ipos = pos + B_ * K_;

  partition_kernel<<<B_, 256, 0, stream>>>(isctx, pos, ipos);
  cvt_all<<<8192, 256, 0, stream>>>(ctx_in_w, tgt_in_w, ctx_out_w, tgt_out_w,
                                    wcat);
  rope_kernel<<<B_ * K_, 256, 0, stream>>>(x, coords, rope, ipos, tok);

  // Merged projection: ctx QKV + tgt KV + tgt Q in one dispatch.
  gemm_proj<<<dim3(48, 8, B_), 256, 0, stream>>>(tok, wcat, ctx_in_b,
                                                 tgt_in_b, qkvc, kvt, qt);

  // ctx self-attention (output overwrites tok rows 0..1023)
  vtrans_kernel<<<dim3(16, H_, B_), 256, 0, stream>>>(
      (const ushort_t*)qkvc, (long long)NCTX_ * 3 * D_, 3 * D_, 2 * D_,
      (ushort_t*)vt);
  attn_mfma<<<dim3(16, H_, B_), 256, 0, stream>>>(
      qkvc, (long long)NCTX_ * 3 * D_, 3 * D_, qkvc + D_,
      (long long)NCTX_ * 3 * D_, 3 * D_, vt, tok, (long long)K_ * D_);
  // tgt cross-attention
  vtrans_kernel<<<dim3(16, H_, B_), 256, 0, stream>>>(
      (const ushort_t*)kvt, (long long)NCTX_ * 2 * D_, 2 * D_, D_,
      (ushort_t*)vt);
  attn_mfma<<<dim3(16, H_, B_), 256, 0, stream>>>(
      qt, (long long)NCTX_ * D_, D_, kvt, (long long)NCTX_ * 2 * D_, 2 * D_,
      vt, tok + (size_t)NCTX_ * D_, (long long)K_ * D_);

  // Merged output projections (fp32, scattered to original order)
  gemm_out<<<dim3(8, 8, 2 * B_), 256, 0, stream>>>(
      tok, wcat + 6291456, ctx_out_b, tgt_out_b, ipos, out);
}

// Round 2
// 422.972 us; speedup vs baseline: 1.0562x; 1.0562x over previous
//
#include <hip/hip_runtime.h>
#include <math.h>

#define B_    4
#define K_    2048
#define D_    1024
#define H_    16
#define NCTX_ 1024

typedef unsigned short ushort_t;
typedef _Float16 f16;
typedef __attribute__((ext_vector_type(8))) _Float16 f16x8;
typedef __attribute__((ext_vector_type(4))) float f32x4;

union U4 {
  f16 h[4];
  ushort4 u;
};

__device__ __forceinline__ void gload16(const void* g, void* l) {
  __builtin_amdgcn_global_load_lds(
      (const __attribute__((address_space(1))) unsigned int*)g,
      (__attribute__((address_space(3))) unsigned int*)l, 16, 0, 0);
}

// ---------------------------------------------------------------------------
// Kernel 1: partition scan (verified R1-R4).
// ---------------------------------------------------------------------------
__global__ __launch_bounds__(256) void partition_kernel(
    const unsigned char* __restrict__ isctx, int* __restrict__ pos,
    int* __restrict__ ipos) {
  const int b = blockIdx.x;
  const int tid = threadIdx.x;
  const int wid = tid >> 6, lane = tid & 63;
  __shared__ int csum[4];
  __shared__ int waveTot[4];
  __shared__ int strideSh;

  int cnt = 0;
  for (int i = 0; i < 32; ++i) cnt += (isctx[tid * 32 + i] != 0);
  for (int off = 32; off; off >>= 1) cnt += __shfl_down(cnt, off, 64);
  if (lane == 0) csum[wid] = cnt;
  __syncthreads();
  if (tid == 0) {
    int t = csum[0] + csum[1] + csum[2] + csum[3];
    strideSh = (t > 2048) ? 1 : ((t > 768) ? 4 : 8);
  }
  __syncthreads();
  const int stride = strideSh;

  const unsigned char* base = isctx + (size_t)b * K_ * stride;
  int f[8];
  int s = 0;
  for (int i = 0; i < 8; ++i) {
    f[i] = base[(size_t)(tid * 8 + i) * stride] != 0;
    s += f[i];
  }
  int inc = s;
  for (int off = 1; off < 64; off <<= 1) {
    int v = __shfl_up(inc, off, 64);
    if (lane >= off) inc += v;
  }
  if (lane == 63) waveTot[wid] = inc;
  __syncthreads();
  int wOff = 0;
  for (int w = 0; w < wid; ++w) wOff += waveTot[w];
  int run = wOff + inc - s;
  for (int i = 0; i < 8; ++i) {
    int k = tid * 8 + i;
    int p;
    if (f[i]) {
      p = run;
      run++;
    } else {
      p = NCTX_ + k - run;
    }
    pos[b * K_ + k] = p;
    ipos[b * K_ + p] = k;
  }
}

// ---------------------------------------------------------------------------
// Kernel 2: RoPE + permute-gather -> f16 token buffer.
// ---------------------------------------------------------------------------
__global__ __launch_bounds__(256) void rope_kernel(
    const float* __restrict__ x, const float* __restrict__ coords,
    const float* __restrict__ cache, const int* __restrict__ ipos,
    f16* __restrict__ tok) {
  const int row = blockIdx.x;
  const int b = row >> 11;
  const int r = row & (K_ - 1);
  const int k = ipos[row];
  const int t = threadIdx.x;

  const float cy = coords[(size_t)(b * K_ + k) * 2 + 0];
  const float cx = coords[(size_t)(b * K_ + k) * 2 + 1];
  const int ypos = (int)fminf(fmaxf(cy / 224.0f * 1023.0f, 0.0f), 1023.0f);
  const int xpos = (int)fminf(fmaxf(cx / 224.0f * 1023.0f, 0.0f), 1023.0f);

  const float4 v = ((const float4*)(x + ((size_t)b * K_ + k) * D_))[t];
  const int e = 4 * t;
  const float* crow;
  int coff;
  if (e < 512) {
    crow = cache + (size_t)xpos * 512;
    coff = e;
  } else {
    crow = cache + (size_t)ypos * 512;
    coff = e - 512;
  }
  const float4 cs = *(const float4*)(crow + coff);
  float o[4];
  o[0] = v.x * cs.x - v.y * cs.y;
  o[1] = v.x * cs.y + v.y * cs.x;
  o[2] = v.z * cs.z - v.w * cs.w;
  o[3] = v.z * cs.w + v.w * cs.z;
  U4 h;
#pragma unroll
  for (int i = 0; i < 4; ++i) h.h[i] = (f16)o[i];
  ((ushort4*)(tok + ((size_t)b * K_ + r) * D_))[t] = h.u;
}

// ---------------------------------------------------------------------------
// Kernel 3: all weights fp32 -> f16, concatenated:
// [0,3M) ctx_in | [3M,5M) tgt_in kv | [5M,6M) tgt_in q | [6M,7M) ctx_out |
// [7M,8M) tgt_out   (M = 1048576 floats)
// ---------------------------------------------------------------------------
__global__ __launch_bounds__(256) void cvt_all(
    const float* __restrict__ ctx_in_w, const float* __restrict__ tgt_in_w,
    const float* __restrict__ ctx_out_w, const float* __restrict__ tgt_out_w,
    f16* __restrict__ dst) {
  const int i4 = blockIdx.x * 256 + threadIdx.x;  // 0..2097151
  const int f = i4 * 4;
  const float* src;
  if (f < 3145728) src = ctx_in_w + f;
  else if (f < 5242880) src = tgt_in_w + (f - 3145728 + 1048576);
  else if (f < 6291456) src = tgt_in_w + (f - 5242880);
  else if (f < 7340032) src = ctx_out_w + (f - 6291456);
  else src = tgt_out_w + (f - 7340032);
  const float4 v = *(const float4*)src;
  U4 u;
  u.h[0] = (f16)v.x;
  u.h[1] = (f16)v.y;
  u.h[2] = (f16)v.z;
  u.h[3] = (f16)v.w;
  ((ushort4*)dst)[i4] = u.u;
}

// ---------------------------------------------------------------------------
// GEMM core v2: BK=32, 3 LDS buffers (48 KB -> 3 blocks/CU), depth-2
// software pipeline with COUNTED vmcnt (T3+T4): tiles t+1,t+2 stay in
// flight ACROSS the barrier; the main loop never drains vmcnt to 0.
// Schedule per K-step:  vmcnt(4); s_barrier; stage(t+2); ds_read+MFMA(t).
//   - vmcnt(4): the 4 loads of tile t (issued 2 iters earlier) are done;
//     tiles t+1/t+2 (<=8 loads) remain outstanding.
//   - stage(t+2) is issued AFTER the barrier => every wave has finished
//     reading buf[(t+2)%3] (it was tile t-1's buffer) -> WAR safe.
//   - ONE barrier per K-step (was 2 with full drain).
// Per-thread global/LDS staging addresses hoisted out of the loop.
// ---------------------------------------------------------------------------
#define GEMM_PRE(AP, WP, Kd)                                                  \
  const int sL0 = wave * 64 + lane, sL1 = 256 + wave * 64 + lane;             \
  const f16* pA0 = (AP) + (size_t)(sL0 & 127) * (Kd) + (sL0 >> 7) * 8;       \
  const f16* pA1 = (AP) + (size_t)(sL1 & 127) * (Kd) + (sL1 >> 7) * 8;       \
  const f16* pW0 = (WP) + (size_t)(sL0 & 127) * (Kd) + (sL0 >> 7) * 8;       \
  const f16* pW1 = (WP) + (size_t)(sL1 & 127) * (Kd) + (sL1 >> 7) * 8;       \
  const int dS0 = sL0 * 8, dS1 = sL1 * 8;

#define GEMM_STAGE32(k0s, bb)                                                 \
  {                                                                           \
    gload16(pA0 + (k0s), &lds[(bb) + dS0]);                                   \
    gload16(pA1 + (k0s), &lds[(bb) + dS1]);                                   \
    gload16(pW0 + (k0s), &lds[(bb) + 4096 + dS0]);                            \
    gload16(pW1 + (k0s), &lds[(bb) + 4096 + dS1]);                            \
  }

#define GEMM_TILE32(bb)                                                       \
  {                                                                           \
    f16x8 af[4], wf[4];                                                       \
    _Pragma("unroll") for (int i = 0; i < 4; ++i) {                           \
      af[i] =                                                                 \
          *(const f16x8*)&lds[(bb) + (quad * 128 + wm + i * 16 + m16) * 8];   \
      wf[i] = *(const f16x8*)&lds[(bb) + 4096 +                               \
                                  (quad * 128 + wn + i * 16 + m16) * 8];      \
    }                                                                         \
    _Pragma("unroll") for (int i = 0; i < 4; ++i)                             \
        _Pragma("unroll") for (int j = 0; j < 4; ++j)                         \
      acc[i][j] = __builtin_amdgcn_mfma_f32_16x16x32_f16(af[i], wf[j],        \
                                                         acc[i][j], 0, 0, 0); \
  }

#define GEMM_CORE32(AP, WP, Kd)                                               \
  f32x4 acc[4][4];                                                            \
  {                                                                           \
    const f32x4 z = {0.f, 0.f, 0.f, 0.f};                                     \
    for (int i = 0; i < 4; ++i)                                               \
      for (int j = 0; j < 4; ++j) acc[i][j] = z;                              \
  }                                                                           \
  GEMM_PRE(AP, WP, Kd)                                                        \
  GEMM_STAGE32(0, 0)                                                          \
  GEMM_STAGE32(32, 8192)                                                      \
  {                                                                           \
    int bb_c = 0, bb_n = 16384;                                               \
    for (int t = 0; t < (Kd) / 32 - 1; ++t) {                                 \
      asm volatile("s_waitcnt vmcnt(4)" ::: "memory");                        \
      __builtin_amdgcn_s_barrier();                                           \
      if (t + 2 < (Kd) / 32) {                                                \
        GEMM_STAGE32((t + 2) * 32, bb_n)                                      \
      }                                                                       \
      GEMM_TILE32(bb_c)                                                       \
      bb_c += 8192;                                                           \
      if (bb_c == 24576) bb_c = 0;                                            \
      bb_n += 8192;                                                           \
      if (bb_n == 24576) bb_n = 0;                                            \
    }                                                                         \
    asm volatile("s_waitcnt vmcnt(0)" ::: "memory");                          \
    __builtin_amdgcn_s_barrier();                                             \
    GEMM_TILE32(bb_c)                                                         \
  }

// ---------------------------------------------------------------------------
// Kernel 4: merged projection GEMM. grid (48, 8, 4):
//   nb < 40: ctx rows x [ctx_in QKV (3072) | tgt_in KV (2048)] -> qkvc / kvt
//   nb >= 40: tgt rows x tgt_in Q (1024) -> qt
// ---------------------------------------------------------------------------
__global__ __launch_bounds__(256, 3) void gemm_proj(
    const f16* __restrict__ tok, const f16* __restrict__ wcat,
    const float* __restrict__ ctx_in_b, const float* __restrict__ tgt_in_b,
    f16* __restrict__ qkvc, f16* __restrict__ kvt, f16* __restrict__ qt) {
  __shared__ f16 lds[24576];
  const int tid = threadIdx.x;
  const int wave = tid >> 6, lane = tid & 63;
  const int quad = lane >> 4, m16 = lane & 15;
  const int nb = blockIdx.x, mb = blockIdx.y, b = blockIdx.z;
  const int wm = (wave & 1) << 6, wn = (wave >> 1) << 6;
  const int m0 = mb * 128;
  const bool isQ = nb >= 40;
  const int n0 = isQ ? (nb - 40) * 128 : nb * 128;
  const f16* AP = tok + (size_t)b * K_ * D_ +
                  (isQ ? (size_t)NCTX_ * D_ : (size_t)0) + (size_t)m0 * D_;
  const f16* WP = wcat + (isQ ? (size_t)5242880 : (size_t)0) +
                  (size_t)n0 * D_;

  GEMM_CORE32(AP, WP, D_)

#pragma unroll
  for (int j = 0; j < 4; ++j) {
    const int col = n0 + wn + j * 16 + m16;
    float bv;
    f16* dst;
    int ldc, dcol;
    if (isQ) {
      bv = tgt_in_b[col];
      dst = qt + (size_t)b * NCTX_ * D_;
      ldc = D_;
      dcol = col;
    } else if (col < 3072) {
      bv = ctx_in_b[col];
      dst = qkvc + (size_t)b * NCTX_ * 3072;
      ldc = 3072;
      dcol = col;
    } else {
      bv = tgt_in_b[D_ + col - 3072];
      dst = kvt + (size_t)b * NCTX_ * 2048;
      ldc = 2048;
      dcol = col - 3072;
    }
#pragma unroll
    for (int i = 0; i < 4; ++i) {
      const int mr = m0 + wm + i * 16 + quad * 4;
#pragma unroll
      for (int r = 0; r < 4; ++r)
        dst[(size_t)(mr + r) * ldc + dcol] = (f16)(acc[i][j][r] + bv);
    }
  }
}

// ---------------------------------------------------------------------------
// Kernel 5: merged output projections. grid (8, 8, 8): b = z&3, sel = z>>2.
// fp32 output scattered to original token order (16-lane 64B segments ->
// already fully coalesced).
// ---------------------------------------------------------------------------
__global__ __launch_bounds__(256, 3) void gemm_out(
    const f16* __restrict__ Atok, const f16* __restrict__ Wbase,
    const float* __restrict__ bias_ctx, const float* __restrict__ bias_tgt,
    const int* __restrict__ ipos, float* __restrict__ out) {
  __shared__ f16 lds[24576];
  const int tid = threadIdx.x;
  const int wave = tid >> 6, lane = tid & 63;
  const int quad = lane >> 4, m16 = lane & 15;
  const int n0 = blockIdx.x * 128, m0 = blockIdx.y * 128;
  const int b = blockIdx.z & 3, sel = blockIdx.z >> 2;
  const int wm = (wave & 1) << 6, wn = (wave >> 1) << 6;
  const f16* AP = Atok + (size_t)b * K_ * D_ + (size_t)sel * NCTX_ * D_ +
                  (size_t)m0 * D_;
  const f16* WP = Wbase + (size_t)sel * 1048576 + (size_t)n0 * D_;
  const float* bias = sel ? bias_tgt : bias_ctx;

  GEMM_CORE32(AP, WP, D_)

#pragma unroll
  for (int j = 0; j < 4; ++j) {
    const int col = n0 + wn + j * 16 + m16;
    const float bv = bias[col];
#pragma unroll
    for (int i = 0; i < 4; ++i) {
      const int mr = m0 + wm + i * 16 + quad * 4;
#pragma unroll
      for (int r = 0; r < 4; ++r) {
        const int orow = ipos[b * K_ + sel * NCTX_ + mr + r];
        out[(size_t)b * K_ * D_ + (size_t)orow * D_ + col] =
            acc[i][j][r] + bv;
      }
    }
  }
}

// ---------------------------------------------------------------------------
// Kernel 6: V transpose (16-bit moves).
// ---------------------------------------------------------------------------
__global__ __launch_bounds__(256) void vtrans_kernel(
    const ushort_t* __restrict__ V, long long sVb, int ldv, int coloff,
    ushort_t* __restrict__ Vt) {
  __shared__ __align__(16) ushort_t tile[64][72];
  const int tblk = blockIdx.x, h = blockIdx.y, b = blockIdx.z;
  const int tid = threadIdx.x;
  const ushort_t* src =
      V + (long long)b * sVb + (size_t)(tblk * 64) * ldv + coloff + h * 64;
#pragma unroll
  for (int j = 0; j < 2; ++j) {
    const int c = j * 256 + tid;
    const int r = c >> 3, dc = c & 7;
    *(uint4*)&tile[r][dc * 8] = *(const uint4*)(src + (size_t)r * ldv + dc * 8);
  }
  __syncthreads();
  ushort_t* dst = Vt + (size_t)(b * H_ + h) * 64 * 1024 + tblk * 64;
#pragma unroll
  for (int j = 0; j < 2; ++j) {
    const int c = j * 256 + tid;
    const int d = c >> 3, tc = c & 7;
    union {
      ushort_t u[8];
      uint4 v;
    } t;
#pragma unroll
    for (int i = 0; i < 8; ++i) t.u[i] = tile[tc * 8 + i][d];
    *(uint4*)(dst + (size_t)d * 1024 + tc * 8) = t.v;
  }
}

// ---------------------------------------------------------------------------
// Kernel 7: MFMA flash attention, f16, single-f16 output (R0 version,
// reverted: the R1 dbuf/setprio edits regressed the total).
// ---------------------------------------------------------------------------
__global__ __launch_bounds__(256) void attn_mfma(
    const f16* __restrict__ Qp, long long sQb, int ldq,
    const f16* __restrict__ Kp, long long sKb, int ldk,
    const f16* __restrict__ Vt, f16* __restrict__ O, long long sOb) {
  __shared__ f16 Qs[4096];
  __shared__ f16 Ks[4096];
  __shared__ f16 Vs[4096];
  __shared__ f16 Ps[4096];
  const int tid = threadIdx.x, wave = tid >> 6, lane = tid & 63;
  const int quad = lane >> 4, m16 = lane & 15;
  const int q0 = blockIdx.x * 64, h = blockIdx.y, b = blockIdx.z;
  const f16* Qb = Qp + (long long)b * sQb + h * 64;
  const f16* Kb = Kp + (long long)b * sKb + h * 64;
  const f16* Vb = Vt + (size_t)(b * H_ + h) * 64 * 1024;

#pragma unroll
  for (int j = 0; j < 2; ++j) {
    const int c = j * 256 + wave * 64 + lane;
    gload16(Qb + (size_t)(q0 + (c & 63)) * ldq + (c >> 6) * 8, &Qs[c * 8]);
  }
  float m_run[4], l_run[4];
#pragma unroll
  for (int r = 0; r < 4; ++r) {
    m_run[r] = -1e30f;
    l_run[r] = 0.f;
  }
  f32x4 Oa[4];
  const f32x4 z = {0.f, 0.f, 0.f, 0.f};
#pragma unroll
  for (int j = 0; j < 4; ++j) Oa[j] = z;

  for (int kt = 0; kt < 16; ++kt) {
#pragma unroll
    for (int j = 0; j < 2; ++j) {
      const int c = j * 256 + wave * 64 + lane;
      gload16(Kb + (size_t)(kt * 64 + (c & 63)) * ldk + (c >> 6) * 8,
              &Ks[c * 8]);
      gload16(Vb + (size_t)(c & 63) * 1024 + kt * 64 + (c >> 6) * 8,
              &Vs[c * 8]);
    }
    __syncthreads();
    const f16x8 qf0 = *(const f16x8*)&Qs[(quad * 64 + wave * 16 + m16) * 8];
    const f16x8 qf1 =
        *(const f16x8*)&Qs[((4 + quad) * 64 + wave * 16 + m16) * 8];
    f32x4 S[4];
#pragma unroll
    for (int jn = 0; jn < 4; ++jn) {
      S[jn] = z;
      const f16x8 kf0 = *(const f16x8*)&Ks[(quad * 64 + jn * 16 + m16) * 8];
      const f16x8 kf1 =
          *(const f16x8*)&Ks[((4 + quad) * 64 + jn * 16 + m16) * 8];
      S[jn] = __builtin_amdgcn_mfma_f32_16x16x32_f16(qf0, kf0, S[jn], 0, 0, 0);
      S[jn] = __builtin_amdgcn_mfma_f32_16x16x32_f16(qf1, kf1, S[jn], 0, 0, 0);
    }
#pragma unroll
    for (int jn = 0; jn < 4; ++jn) S[jn] *= 0.125f;
    float mnew[4], al[4], rs[4];
#pragma unroll
    for (int r = 0; r < 4; ++r) {
      float mx = fmaxf(fmaxf(S[0][r], S[1][r]), fmaxf(S[2][r], S[3][r]));
      mx = fmaxf(mx, __shfl_xor(mx, 1, 64));
      mx = fmaxf(mx, __shfl_xor(mx, 2, 64));
      mx = fmaxf(mx, __shfl_xor(mx, 4, 64));
      mx = fmaxf(mx, __shfl_xor(mx, 8, 64));
      mnew[r] = fmaxf(m_run[r], mx);
      al[r] = __expf(m_run[r] - mnew[r]);
      m_run[r] = mnew[r];
      rs[r] = 0.f;
    }
#pragma unroll
    for (int jn = 0; jn < 4; ++jn)
#pragma unroll
      for (int r = 0; r < 4; ++r) {
        const float p = __expf(S[jn][r] - mnew[r]);
        S[jn][r] = p;
        rs[r] += p;
      }
#pragma unroll
    for (int r = 0; r < 4; ++r) {
      float s = rs[r];
      s += __shfl_xor(s, 1, 64);
      s += __shfl_xor(s, 2, 64);
      s += __shfl_xor(s, 4, 64);
      s += __shfl_xor(s, 8, 64);
      l_run[r] = l_run[r] * al[r] + s;
    }
#pragma unroll
    for (int j = 0; j < 4; ++j) {
      Oa[j][0] *= al[0];
      Oa[j][1] *= al[1];
      Oa[j][2] *= al[2];
      Oa[j][3] *= al[3];
    }
    f16* Pw = Ps + wave * 1024;
#pragma unroll
    for (int jn = 0; jn < 4; ++jn)
#pragma unroll
      for (int r = 0; r < 4; ++r)
        Pw[((jn * 2 + (m16 >> 3)) * 16 + quad * 4 + r) * 8 + (m16 & 7)] =
            (f16)S[jn][r];
    const f16x8 pf0 = *(const f16x8*)&Pw[(quad * 16 + m16) * 8];
    const f16x8 pf1 = *(const f16x8*)&Pw[((4 + quad) * 16 + m16) * 8];
#pragma unroll
    for (int jd = 0; jd < 4; ++jd) {
      const f16x8 vf0 = *(const f16x8*)&Vs[(quad * 64 + jd * 16 + m16) * 8];
      const f16x8 vf1 =
          *(const f16x8*)&Vs[((4 + quad) * 64 + jd * 16 + m16) * 8];
      Oa[jd] = __builtin_amdgcn_mfma_f32_16x16x32_f16(pf0, vf0, Oa[jd], 0, 0, 0);
      Oa[jd] = __builtin_amdgcn_mfma_f32_16x16x32_f16(pf1, vf1, Oa[jd], 0, 0, 0);
    }
    __syncthreads();
  }
#pragma unroll
  for (int jd = 0; jd < 4; ++jd)
#pragma unroll
    for (int r = 0; r < 4; ++r) {
      const float v = Oa[jd][r] / l_run[r];
      const size_t off = (long long)b * sOb +
                         (size_t)(q0 + wave * 16 + quad * 4 + r) * D_ + h * 64 +
                         jd * 16 + m16;
      O[off] = (f16)v;
    }
}

// ---------------------------------------------------------------------------
extern "C" void kernel_launch(void* const* d_in, const int* in_sizes, int n_in,
                              void* d_out, int out_size, void* d_ws,
                              size_t ws_size, hipStream_t stream) {
  const float* x = (const float*)d_in[0];
  const float* coords = (const float*)d_in[1];
  const unsigned char* isctx = (const unsigned char*)d_in[2];
  const float* rope = (const float*)d_in[3];
  const float* ctx_in_w = (const float*)d_in[4];
  const float* ctx_in_b = (const float*)d_in[5];
  const float* ctx_out_w = (const float*)d_in[6];
  const float* ctx_out_b = (const float*)d_in[7];
  const float* tgt_in_w = (const float*)d_in[8];
  const float* tgt_in_b = (const float*)d_in[9];
  const float* tgt_out_w = (const float*)d_in[10];
  const float* tgt_out_b = (const float*)d_in[11];
  float* out = (float*)d_out;

  // ws layout (f16 units): tok 8M | wcat 8M | qkvc 12M | kvt 8M | qt 4M |
  // vt 4M | pos/ipos ints
  f16* ws = (f16*)d_ws;
  f16* tok = ws;
  f16* wcat = tok + 8388608;
  f16* qkvc = wcat + 8388608;
  f16* kvt = qkvc + 12582912;
  f16* qt = kvt + 8388608;
  f16* vt = qt + 4194304;
  int* pos = (int*)(vt + 4194304);
  int* ipos = pos + B_ * K_;

  partition_kernel<<<B_, 256, 0, stream>>>(isctx, pos, ipos);
  cvt_all<<<8192, 256, 0, stream>>>(ctx_in_w, tgt_in_w, ctx_out_w, tgt_out_w,
                                    wcat);
  rope_kernel<<<B_ * K_, 256, 0, stream>>>(x, coords, rope, ipos, tok);

  // Merged projection: ctx QKV + tgt KV + tgt Q in one dispatch.
  gemm_proj<<<dim3(48, 8, B_), 256, 0, stream>>>(tok, wcat, ctx_in_b,
                                                 tgt_in_b, qkvc, kvt, qt);

  // ctx self-attention (output overwrites tok rows 0..1023)
  vtrans_kernel<<<dim3(16, H_, B_), 256, 0, stream>>>(
      (const ushort_t*)qkvc, (long long)NCTX_ * 3 * D_, 3 * D_, 2 * D_,
      (ushort_t*)vt);
  attn_mfma<<<dim3(16, H_, B_), 256, 0, stream>>>(
      qkvc, (long long)NCTX_ * 3 * D_, 3 * D_, qkvc + D_,
      (long long)NCTX_ * 3 * D_, 3 * D_, vt, tok, (long long)K_ * D_);
  // tgt cross-attention
  vtrans_kernel<<<dim3(16, H_, B_), 256, 0, stream>>>(
      (const ushort_t*)kvt, (long long)NCTX_ * 2 * D_, 2 * D_, D_,
      (ushort_t*)vt);
  attn_mfma<<<dim3(16, H_, B_), 256, 0, stream>>>(
      qt, (long long)NCTX_ * D_, D_, kvt, (long long)NCTX_ * 2 * D_, 2 * D_,
      vt, tok + (size_t)NCTX_ * D_, (long long)K_ * D_);

  // Merged output projections (fp32, scattered to original order)
  gemm_out<<<dim3(8, 8, 2 * B_), 256, 0, stream>>>(
      tok, wcat + 6291456, ctx_out_b, tgt_out_b, ipos, out);
}

// Round 3
// 353.882 us; speedup vs baseline: 1.2624x; 1.1952x over previous
//
#include <hip/hip_runtime.h>
#include <math.h>

#define B_    4
#define K_    2048
#define D_    1024
#define H_    16
#define NCTX_ 1024

typedef unsigned short ushort_t;
typedef _Float16 f16;
typedef __attribute__((ext_vector_type(8))) _Float16 f16x8;
typedef __attribute__((ext_vector_type(4))) float f32x4;

union U4 {
  f16 h[4];
  ushort4 u;
};

__device__ __forceinline__ void gload16(const void* g, void* l) {
  __builtin_amdgcn_global_load_lds(
      (const __attribute__((address_space(1))) unsigned int*)g,
      (__attribute__((address_space(3))) unsigned int*)l, 16, 0, 0);
}

// ---------------------------------------------------------------------------
// Kernel 1: partition scan (verified R1-R4).
// ---------------------------------------------------------------------------
__global__ __launch_bounds__(256) void partition_kernel(
    const unsigned char* __restrict__ isctx, int* __restrict__ pos,
    int* __restrict__ ipos) {
  const int b = blockIdx.x;
  const int tid = threadIdx.x;
  const int wid = tid >> 6, lane = tid & 63;
  __shared__ int csum[4];
  __shared__ int waveTot[4];
  __shared__ int strideSh;

  int cnt = 0;
  for (int i = 0; i < 32; ++i) cnt += (isctx[tid * 32 + i] != 0);
  for (int off = 32; off; off >>= 1) cnt += __shfl_down(cnt, off, 64);
  if (lane == 0) csum[wid] = cnt;
  __syncthreads();
  if (tid == 0) {
    int t = csum[0] + csum[1] + csum[2] + csum[3];
    strideSh = (t > 2048) ? 1 : ((t > 768) ? 4 : 8);
  }
  __syncthreads();
  const int stride = strideSh;

  const unsigned char* base = isctx + (size_t)b * K_ * stride;
  int f[8];
  int s = 0;
  for (int i = 0; i < 8; ++i) {
    f[i] = base[(size_t)(tid * 8 + i) * stride] != 0;
    s += f[i];
  }
  int inc = s;
  for (int off = 1; off < 64; off <<= 1) {
    int v = __shfl_up(inc, off, 64);
    if (lane >= off) inc += v;
  }
  if (lane == 63) waveTot[wid] = inc;
  __syncthreads();
  int wOff = 0;
  for (int w = 0; w < wid; ++w) wOff += waveTot[w];
  int run = wOff + inc - s;
  for (int i = 0; i < 8; ++i) {
    int k = tid * 8 + i;
    int p;
    if (f[i]) {
      p = run;
      run++;
    } else {
      p = NCTX_ + k - run;
    }
    pos[b * K_ + k] = p;
    ipos[b * K_ + p] = k;
  }
}

// ---------------------------------------------------------------------------
// Kernel 2: RoPE + permute-gather -> f16 token buffer.
// ---------------------------------------------------------------------------
__global__ __launch_bounds__(256) void rope_kernel(
    const float* __restrict__ x, const float* __restrict__ coords,
    const float* __restrict__ cache, const int* __restrict__ ipos,
    f16* __restrict__ tok) {
  const int row = blockIdx.x;
  const int b = row >> 11;
  const int r = row & (K_ - 1);
  const int k = ipos[row];
  const int t = threadIdx.x;

  const float cy = coords[(size_t)(b * K_ + k) * 2 + 0];
  const float cx = coords[(size_t)(b * K_ + k) * 2 + 1];
  const int ypos = (int)fminf(fmaxf(cy / 224.0f * 1023.0f, 0.0f), 1023.0f);
  const int xpos = (int)fminf(fmaxf(cx / 224.0f * 1023.0f, 0.0f), 1023.0f);

  const float4 v = ((const float4*)(x + ((size_t)b * K_ + k) * D_))[t];
  const int e = 4 * t;
  const float* crow;
  int coff;
  if (e < 512) {
    crow = cache + (size_t)xpos * 512;
    coff = e;
  } else {
    crow = cache + (size_t)ypos * 512;
    coff = e - 512;
  }
  const float4 cs = *(const float4*)(crow + coff);
  float o[4];
  o[0] = v.x * cs.x - v.y * cs.y;
  o[1] = v.x * cs.y + v.y * cs.x;
  o[2] = v.z * cs.z - v.w * cs.w;
  o[3] = v.z * cs.w + v.w * cs.z;
  U4 h;
#pragma unroll
  for (int i = 0; i < 4; ++i) h.h[i] = (f16)o[i];
  ((ushort4*)(tok + ((size_t)b * K_ + r) * D_))[t] = h.u;
}

// ---------------------------------------------------------------------------
// Kernel 3: all weights fp32 -> f16, concatenated:
// [0,3M) ctx_in | [3M,5M) tgt_in kv | [5M,6M) tgt_in q | [6M,7M) ctx_out |
// [7M,8M) tgt_out   (M = 1048576 floats)
// ---------------------------------------------------------------------------
__global__ __launch_bounds__(256) void cvt_all(
    const float* __restrict__ ctx_in_w, const float* __restrict__ tgt_in_w,
    const float* __restrict__ ctx_out_w, const float* __restrict__ tgt_out_w,
    f16* __restrict__ dst) {
  const int i4 = blockIdx.x * 256 + threadIdx.x;  // 0..2097151
  const int f = i4 * 4;
  const float* src;
  if (f < 3145728) src = ctx_in_w + f;
  else if (f < 5242880) src = tgt_in_w + (f - 3145728 + 1048576);
  else if (f < 6291456) src = tgt_in_w + (f - 5242880);
  else if (f < 7340032) src = ctx_out_w + (f - 6291456);
  else src = tgt_out_w + (f - 7340032);
  const float4 v = *(const float4*)src;
  U4 u;
  u.h[0] = (f16)v.x;
  u.h[1] = (f16)v.y;
  u.h[2] = (f16)v.z;
  u.h[3] = (f16)v.w;
  ((ushort4*)dst)[i4] = u.u;
}

// ---------------------------------------------------------------------------
// GEMM core v3: COALESCED staging. R0-R2 staged with lane->row mapping
// (64 scattered cache lines per gload16 instruction); all three schedules
// measured identical 119-120us -> the per-request VMEM floor, not the
// schedule, is the limiter. New mapping: 8-lane groups read one contiguous
// 128-B row segment (full BK=64 row) -> 8 segments/instr (8x fewer
// requests). LDS becomes row-major [128][64 f16] (128-B row stride), which
// needs the both-sides XOR swizzle (rule #21 / G4): global source k-chunk
// pre-permuted by ^(row&7), read side applies the same XOR (involution).
// 16-lane read groups then hit 8 distinct 16-B slots -> 2-way, free.
// BK=64, double-buffered (64 KB -> 2 blocks/CU), stage(t+1) before
// compute(t), counted vmcnt(8) in the main loop (never 0).
// ---------------------------------------------------------------------------
#define GEMM_PRE(AP, WP, Kd)                                                  \
  const int rb_ = wave * 8 + (lane >> 3);         /* row 0..31 (j adds 32) */ \
  const int kk_ = ((lane & 7) ^ (lane >> 3)) * 8; /* pre-swizzled k-chunk */  \
  const f16* gA_ = (AP) + (size_t)rb_ * (Kd) + kk_;                           \
  const f16* gW_ = (WP) + (size_t)rb_ * (Kd) + kk_;                           \
  const int lA_ = wave * 8 * 64 + lane * 8; /* == row*64 + kkchunk*8 */

#define GEMM_STAGE(k0s, bb)                                                   \
  _Pragma("unroll") for (int j = 0; j < 4; ++j) {                             \
    gload16(gA_ + (size_t)j * 32 * Kd_ + (k0s), &lds[(bb) + j * 2048 + lA_]); \
    gload16(gW_ + (size_t)j * 32 * Kd_ + (k0s),                               \
            &lds[(bb) + 8192 + j * 2048 + lA_]);                              \
  }

#define GEMM_TILE(bb)                                                         \
  _Pragma("unroll") for (int kh = 0; kh < 2; ++kh) {                          \
    f16x8 af[4], wf[4];                                                       \
    _Pragma("unroll") for (int i = 0; i < 4; ++i) {                           \
      const int ca = ((kh * 4 + quad) ^ (m16 & 7)) * 8;                       \
      af[i] = *(const f16x8*)&lds[(bb) + (wm + i * 16 + m16) * 64 + ca];      \
      wf[i] =                                                                 \
          *(const f16x8*)&lds[(bb) + 8192 + (wn + i * 16 + m16) * 64 + ca];   \
    }                                                                         \
    _Pragma("unroll") for (int i = 0; i < 4; ++i)                             \
        _Pragma("unroll") for (int j = 0; j < 4; ++j)                         \
      acc[i][j] = __builtin_amdgcn_mfma_f32_16x16x32_f16(af[i], wf[j],        \
                                                         acc[i][j], 0, 0, 0); \
  }

#define GEMM_CORE(AP, WP, Kd)                                                 \
  f32x4 acc[4][4];                                                            \
  {                                                                           \
    const f32x4 z = {0.f, 0.f, 0.f, 0.f};                                     \
    for (int i = 0; i < 4; ++i)                                               \
      for (int j = 0; j < 4; ++j) acc[i][j] = z;                              \
  }                                                                           \
  const int Kd_ = (Kd);                                                       \
  GEMM_PRE(AP, WP, Kd_)                                                       \
  GEMM_STAGE(0, 0)                                                            \
  for (int t = 0; t < Kd_ / 64; ++t) {                                        \
    const int cb = (t & 1) * 16384;                                           \
    if (t + 1 < Kd_ / 64) {                                                   \
      GEMM_STAGE((t + 1) * 64, ((t + 1) & 1) * 16384)                         \
      asm volatile("s_waitcnt vmcnt(8)" ::: "memory");                        \
    } else {                                                                  \
      asm volatile("s_waitcnt vmcnt(0)" ::: "memory");                        \
    }                                                                         \
    __builtin_amdgcn_s_barrier();                                             \
    asm volatile("" ::: "memory");                                            \
    GEMM_TILE(cb)                                                             \
    asm volatile("" ::: "memory");                                            \
    __builtin_amdgcn_s_barrier();                                             \
  }

// ---------------------------------------------------------------------------
// Kernel 4: merged projection GEMM. grid (48, 8, 4):
//   nb < 40: ctx rows x [ctx_in QKV (3072) | tgt_in KV (2048)] -> qkvc / kvt
//   nb >= 40: tgt rows x tgt_in Q (1024) -> qt
// ---------------------------------------------------------------------------
__global__ __launch_bounds__(256, 2) void gemm_proj(
    const f16* __restrict__ tok, const f16* __restrict__ wcat,
    const float* __restrict__ ctx_in_b, const float* __restrict__ tgt_in_b,
    f16* __restrict__ qkvc, f16* __restrict__ kvt, f16* __restrict__ qt) {
  __shared__ f16 lds[32768];
  const int tid = threadIdx.x;
  const int wave = tid >> 6, lane = tid & 63;
  const int quad = lane >> 4, m16 = lane & 15;
  const int nb = blockIdx.x, mb = blockIdx.y, b = blockIdx.z;
  const int wm = (wave & 1) << 6, wn = (wave >> 1) << 6;
  const int m0 = mb * 128;
  const bool isQ = nb >= 40;
  const int n0 = isQ ? (nb - 40) * 128 : nb * 128;
  const f16* AP = tok + (size_t)b * K_ * D_ +
                  (isQ ? (size_t)NCTX_ * D_ : (size_t)0) + (size_t)m0 * D_;
  const f16* WP = wcat + (isQ ? (size_t)5242880 : (size_t)0) +
                  (size_t)n0 * D_;

  GEMM_CORE(AP, WP, D_)

#pragma unroll
  for (int j = 0; j < 4; ++j) {
    const int col = n0 + wn + j * 16 + m16;
    float bv;
    f16* dst;
    int ldc, dcol;
    if (isQ) {
      bv = tgt_in_b[col];
      dst = qt + (size_t)b * NCTX_ * D_;
      ldc = D_;
      dcol = col;
    } else if (col < 3072) {
      bv = ctx_in_b[col];
      dst = qkvc + (size_t)b * NCTX_ * 3072;
      ldc = 3072;
      dcol = col;
    } else {
      bv = tgt_in_b[D_ + col - 3072];
      dst = kvt + (size_t)b * NCTX_ * 2048;
      ldc = 2048;
      dcol = col - 3072;
    }
#pragma unroll
    for (int i = 0; i < 4; ++i) {
      const int mr = m0 + wm + i * 16 + quad * 4;
#pragma unroll
      for (int r = 0; r < 4; ++r)
        dst[(size_t)(mr + r) * ldc + dcol] = (f16)(acc[i][j][r] + bv);
    }
  }
}

// ---------------------------------------------------------------------------
// Kernel 5: merged output projections. grid (8, 8, 8): b = z&3, sel = z>>2.
// fp32 output scattered to original token order (16-lane 64B segments ->
// already fully coalesced).
// ---------------------------------------------------------------------------
__global__ __launch_bounds__(256, 2) void gemm_out(
    const f16* __restrict__ Atok, const f16* __restrict__ Wbase,
    const float* __restrict__ bias_ctx, const float* __restrict__ bias_tgt,
    const int* __restrict__ ipos, float* __restrict__ out) {
  __shared__ f16 lds[32768];
  const int tid = threadIdx.x;
  const int wave = tid >> 6, lane = tid & 63;
  const int quad = lane >> 4, m16 = lane & 15;
  const int n0 = blockIdx.x * 128, m0 = blockIdx.y * 128;
  const int b = blockIdx.z & 3, sel = blockIdx.z >> 2;
  const int wm = (wave & 1) << 6, wn = (wave >> 1) << 6;
  const f16* AP = Atok + (size_t)b * K_ * D_ + (size_t)sel * NCTX_ * D_ +
                  (size_t)m0 * D_;
  const f16* WP = Wbase + (size_t)sel * 1048576 + (size_t)n0 * D_;
  const float* bias = sel ? bias_tgt : bias_ctx;

  GEMM_CORE(AP, WP, D_)

#pragma unroll
  for (int j = 0; j < 4; ++j) {
    const int col = n0 + wn + j * 16 + m16;
    const float bv = bias[col];
#pragma unroll
    for (int i = 0; i < 4; ++i) {
      const int mr = m0 + wm + i * 16 + quad * 4;
#pragma unroll
      for (int r = 0; r < 4; ++r) {
        const int orow = ipos[b * K_ + sel * NCTX_ + mr + r];
        out[(size_t)b * K_ * D_ + (size_t)orow * D_ + col] =
            acc[i][j][r] + bv;
      }
    }
  }
}

// ---------------------------------------------------------------------------
// Kernel 6: V transpose (16-bit moves).
// ---------------------------------------------------------------------------
__global__ __launch_bounds__(256) void vtrans_kernel(
    const ushort_t* __restrict__ V, long long sVb, int ldv, int coloff,
    ushort_t* __restrict__ Vt) {
  __shared__ __align__(16) ushort_t tile[64][72];
  const int tblk = blockIdx.x, h = blockIdx.y, b = blockIdx.z;
  const int tid = threadIdx.x;
  const ushort_t* src =
      V + (long long)b * sVb + (size_t)(tblk * 64) * ldv + coloff + h * 64;
#pragma unroll
  for (int j = 0; j < 2; ++j) {
    const int c = j * 256 + tid;
    const int r = c >> 3, dc = c & 7;
    *(uint4*)&tile[r][dc * 8] = *(const uint4*)(src + (size_t)r * ldv + dc * 8);
  }
  __syncthreads();
  ushort_t* dst = Vt + (size_t)(b * H_ + h) * 64 * 1024 + tblk * 64;
#pragma unroll
  for (int j = 0; j < 2; ++j) {
    const int c = j * 256 + tid;
    const int d = c >> 3, tc = c & 7;
    union {
      ushort_t u[8];
      uint4 v;
    } t;
#pragma unroll
    for (int i = 0; i < 8; ++i) t.u[i] = tile[tc * 8 + i][d];
    *(uint4*)(dst + (size_t)d * 1024 + tc * 8) = t.v;
  }
}

// ---------------------------------------------------------------------------
// Kernel 7: MFMA flash attention, f16, single-f16 output (R0 version).
// ---------------------------------------------------------------------------
__global__ __launch_bounds__(256) void attn_mfma(
    const f16* __restrict__ Qp, long long sQb, int ldq,
    const f16* __restrict__ Kp, long long sKb, int ldk,
    const f16* __restrict__ Vt, f16* __restrict__ O, long long sOb) {
  __shared__ f16 Qs[4096];
  __shared__ f16 Ks[4096];
  __shared__ f16 Vs[4096];
  __shared__ f16 Ps[4096];
  const int tid = threadIdx.x, wave = tid >> 6, lane = tid & 63;
  const int quad = lane >> 4, m16 = lane & 15;
  const int q0 = blockIdx.x * 64, h = blockIdx.y, b = blockIdx.z;
  const f16* Qb = Qp + (long long)b * sQb + h * 64;
  const f16* Kb = Kp + (long long)b * sKb + h * 64;
  const f16* Vb = Vt + (size_t)(b * H_ + h) * 64 * 1024;

#pragma unroll
  for (int j = 0; j < 2; ++j) {
    const int c = j * 256 + wave * 64 + lane;
    gload16(Qb + (size_t)(q0 + (c & 63)) * ldq + (c >> 6) * 8, &Qs[c * 8]);
  }
  float m_run[4], l_run[4];
#pragma unroll
  for (int r = 0; r < 4; ++r) {
    m_run[r] = -1e30f;
    l_run[r] = 0.f;
  }
  f32x4 Oa[4];
  const f32x4 z = {0.f, 0.f, 0.f, 0.f};
#pragma unroll
  for (int j = 0; j < 4; ++j) Oa[j] = z;

  for (int kt = 0; kt < 16; ++kt) {
#pragma unroll
    for (int j = 0; j < 2; ++j) {
      const int c = j * 256 + wave * 64 + lane;
      gload16(Kb + (size_t)(kt * 64 + (c & 63)) * ldk + (c >> 6) * 8,
              &Ks[c * 8]);
      gload16(Vb + (size_t)(c & 63) * 1024 + kt * 64 + (c >> 6) * 8,
              &Vs[c * 8]);
    }
    __syncthreads();
    const f16x8 qf0 = *(const f16x8*)&Qs[(quad * 64 + wave * 16 + m16) * 8];
    const f16x8 qf1 =
        *(const f16x8*)&Qs[((4 + quad) * 64 + wave * 16 + m16) * 8];
    f32x4 S[4];
#pragma unroll
    for (int jn = 0; jn < 4; ++jn) {
      S[jn] = z;
      const f16x8 kf0 = *(const f16x8*)&Ks[(quad * 64 + jn * 16 + m16) * 8];
      const f16x8 kf1 =
          *(const f16x8*)&Ks[((4 + quad) * 64 + jn * 16 + m16) * 8];
      S[jn] = __builtin_amdgcn_mfma_f32_16x16x32_f16(qf0, kf0, S[jn], 0, 0, 0);
      S[jn] = __builtin_amdgcn_mfma_f32_16x16x32_f16(qf1, kf1, S[jn], 0, 0, 0);
    }
#pragma unroll
    for (int jn = 0; jn < 4; ++jn) S[jn] *= 0.125f;
    float mnew[4], al[4], rs[4];
#pragma unroll
    for (int r = 0; r < 4; ++r) {
      float mx = fmaxf(fmaxf(S[0][r], S[1][r]), fmaxf(S[2][r], S[3][r]));
      mx = fmaxf(mx, __shfl_xor(mx, 1, 64));
      mx = fmaxf(mx, __shfl_xor(mx, 2, 64));
      mx = fmaxf(mx, __shfl_xor(mx, 4, 64));
      mx = fmaxf(mx, __shfl_xor(mx, 8, 64));
      mnew[r] = fmaxf(m_run[r], mx);
      al[r] = __expf(m_run[r] - mnew[r]);
      m_run[r] = mnew[r];
      rs[r] = 0.f;
    }
#pragma unroll
    for (int jn = 0; jn < 4; ++jn)
#pragma unroll
      for (int r = 0; r < 4; ++r) {
        const float p = __expf(S[jn][r] - mnew[r]);
        S[jn][r] = p;
        rs[r] += p;
      }
#pragma unroll
    for (int r = 0; r < 4; ++r) {
      float s = rs[r];
      s += __shfl_xor(s, 1, 64);
      s += __shfl_xor(s, 2, 64);
      s += __shfl_xor(s, 4, 64);
      s += __shfl_xor(s, 8, 64);
      l_run[r] = l_run[r] * al[r] + s;
    }
#pragma unroll
    for (int j = 0; j < 4; ++j) {
      Oa[j][0] *= al[0];
      Oa[j][1] *= al[1];
      Oa[j][2] *= al[2];
      Oa[j][3] *= al[3];
    }
    f16* Pw = Ps + wave * 1024;
#pragma unroll
    for (int jn = 0; jn < 4; ++jn)
#pragma unroll
      for (int r = 0; r < 4; ++r)
        Pw[((jn * 2 + (m16 >> 3)) * 16 + quad * 4 + r) * 8 + (m16 & 7)] =
            (f16)S[jn][r];
    const f16x8 pf0 = *(const f16x8*)&Pw[(quad * 16 + m16) * 8];
    const f16x8 pf1 = *(const f16x8*)&Pw[((4 + quad) * 16 + m16) * 8];
#pragma unroll
    for (int jd = 0; jd < 4; ++jd) {
      const f16x8 vf0 = *(const f16x8*)&Vs[(quad * 64 + jd * 16 + m16) * 8];
      const f16x8 vf1 =
          *(const f16x8*)&Vs[((4 + quad) * 64 + jd * 16 + m16) * 8];
      Oa[jd] = __builtin_amdgcn_mfma_f32_16x16x32_f16(pf0, vf0, Oa[jd], 0, 0, 0);
      Oa[jd] = __builtin_amdgcn_mfma_f32_16x16x32_f16(pf1, vf1, Oa[jd], 0, 0, 0);
    }
    __syncthreads();
  }
#pragma unroll
  for (int jd = 0; jd < 4; ++jd)
#pragma unroll
    for (int r = 0; r < 4; ++r) {
      const float v = Oa[jd][r] / l_run[r];
      const size_t off = (long long)b * sOb +
                         (size_t)(q0 + wave * 16 + quad * 4 + r) * D_ + h * 64 +
                         jd * 16 + m16;
      O[off] = (f16)v;
    }
}

// ---------------------------------------------------------------------------
extern "C" void kernel_launch(void* const* d_in, const int* in_sizes, int n_in,
                              void* d_out, int out_size, void* d_ws,
                              size_t ws_size, hipStream_t stream) {
  const float* x = (const float*)d_in[0];
  const float* coords = (const float*)d_in[1];
  const unsigned char* isctx = (const unsigned char*)d_in[2];
  const float* rope = (const float*)d_in[3];
  const float* ctx_in_w = (const float*)d_in[4];
  const float* ctx_in_b = (const float*)d_in[5];
  const float* ctx_out_w = (const float*)d_in[6];
  const float* ctx_out_b = (const float*)d_in[7];
  const float* tgt_in_w = (const float*)d_in[8];
  const float* tgt_in_b = (const float*)d_in[9];
  const float* tgt_out_w = (const float*)d_in[10];
  const float* tgt_out_b = (const float*)d_in[11];
  float* out = (float*)d_out;

  // ws layout (f16 units): tok 8M | wcat 8M | qkvc 12M | kvt 8M | qt 4M |
  // vt 4M | pos/ipos ints
  f16* ws = (f16*)d_ws;
  f16* tok = ws;
  f16* wcat = tok + 8388608;
  f16* qkvc = wcat + 8388608;
  f16* kvt = qkvc + 12582912;
  f16* qt = kvt + 8388608;
  f16* vt = qt + 4194304;
  int* pos = (int*)(vt + 4194304);
  int* ipos = pos + B_ * K_;

  partition_kernel<<<B_, 256, 0, stream>>>(isctx, pos, ipos);
  cvt_all<<<8192, 256, 0, stream>>>(ctx_in_w, tgt_in_w, ctx_out_w, tgt_out_w,
                                    wcat);
  rope_kernel<<<B_ * K_, 256, 0, stream>>>(x, coords, rope, ipos, tok);

  // Merged projection: ctx QKV + tgt KV + tgt Q in one dispatch.
  gemm_proj<<<dim3(48, 8, B_), 256, 0, stream>>>(tok, wcat, ctx_in_b,
                                                 tgt_in_b, qkvc, kvt, qt);

  // ctx self-attention (output overwrites tok rows 0..1023)
  vtrans_kernel<<<dim3(16, H_, B_), 256, 0, stream>>>(
      (const ushort_t*)qkvc, (long long)NCTX_ * 3 * D_, 3 * D_, 2 * D_,
      (ushort_t*)vt);
  attn_mfma<<<dim3(16, H_, B_), 256, 0, stream>>>(
      qkvc, (long long)NCTX_ * 3 * D_, 3 * D_, qkvc + D_,
      (long long)NCTX_ * 3 * D_, 3 * D_, vt, tok, (long long)K_ * D_);
  // tgt cross-attention
  vtrans_kernel<<<dim3(16, H_, B_), 256, 0, stream>>>(
      (const ushort_t*)kvt, (long long)NCTX_ * 2 * D_, 2 * D_, D_,
      (ushort_t*)vt);
  attn_mfma<<<dim3(16, H_, B_), 256, 0, stream>>>(
      qt, (long long)NCTX_ * D_, D_, kvt, (long long)NCTX_ * 2 * D_, 2 * D_,
      vt, tok + (size_t)NCTX_ * D_, (long long)K_ * D_);

  // Merged output projections (fp32, scattered to original order)
  gemm_out<<<dim3(8, 8, 2 * B_), 256, 0, stream>>>(
      tok, wcat + 6291456, ctx_out_b, tgt_out_b, ipos, out);
}